// Round 12
// baseline (1258.810 us; speedup 1.0000x reference)
//
#include <hip/hip_runtime.h>
#include <stdint.h>

typedef unsigned int u32;
typedef unsigned short u16;
typedef __attribute__((ext_vector_type(8))) short bf16x8;
typedef __attribute__((ext_vector_type(4))) float f32x4;
typedef __attribute__((ext_vector_type(8))) unsigned int u32x8_t;
typedef __attribute__((ext_vector_type(4))) unsigned int u32x4_t;

#define BCAP 16384u   // per-bucket item capacity (mean fill ~11.5K, 46 sigma margin)

struct Ptr7 { const float* p[7]; };

__device__ __forceinline__ int rfl(int v) { return __builtin_amdgcn_readfirstlane(v); }
__device__ __forceinline__ u16 f2bf(float f) {
    u32 u = __float_as_uint(f);
    u32 r = (u + 0x7FFFu + ((u >> 16) & 1u)) >> 16;
    return (u16)r;
}
__device__ __forceinline__ float bf2f(u16 h) { return __uint_as_float((u32)h << 16); }

// ================= bucketed CSR build, 512 fixed-capacity buckets of 512 nodes ===========
// tmp item = src(18b) | k(3b)<<18 | dstlocal(9b)<<21 ; bucket = target >> 9
// final entry = (k<<28) | (src<<7)   (pre-scaled byte offset into 128B h-rows)
// node segments padded to 8-item multiples (pad carried in unused k=7 slot)

__global__ void k_init_cur(u32* __restrict__ g) {
    int i = blockIdx.x * 256 + threadIdx.x;
    if (i < 512) g[i] = (u32)i << 14;     // b * BCAP
}

// single-pass: 16 edges/thread held in registers (one vmcnt batch), then hist/alloc/scatter
__global__ __launch_bounds__(256)
void k_passA(const int* __restrict__ ei, const int* __restrict__ ty, int E,
             u32* __restrict__ gcursor, u32* __restrict__ tmpItems) {
    __shared__ u32 hist[512], gb[512], cur[512];
    int tid = threadIdx.x;
    int e0 = blockIdx.x * 4096;
    int s[16], d[16], t[16];
#pragma unroll
    for (int i = 0; i < 16; i++) {
        int e = e0 + i * 256 + tid;
        if (e < E) { s[i] = ei[e]; d[i] = ei[E + e]; t[i] = ty[e]; }
        else t[i] = 0;
    }
    hist[tid] = 0; hist[tid + 256] = 0;
    __syncthreads();
#pragma unroll
    for (int i = 0; i < 16; i++) {
        if (t[i] >= 1) atomicAdd(&hist[(u32)d[i] >> 9], 1u);
        if (t[i] >= 2) atomicAdd(&hist[(u32)s[i] >> 9], 1u);
    }
    __syncthreads();
    u32 h0 = hist[tid], h1 = hist[tid + 256];
    gb[tid] = h0 ? atomicAdd(&gcursor[tid], h0) : 0u;
    gb[tid + 256] = h1 ? atomicAdd(&gcursor[tid + 256], h1) : 0u;
    cur[tid] = 0; cur[tid + 256] = 0;
    __syncthreads();
#pragma unroll
    for (int i = 0; i < 16; i++) {
        if (t[i] >= 1) {
            u32 b = (u32)d[i] >> 9;
            u32 slot = atomicAdd(&cur[b], 1u);
            u32 pos = gb[b] + slot;
            if (pos < ((b + 1u) << 14))
                tmpItems[pos] = (u32)s[i] | ((u32)(t[i] - 1) << 18) | (((u32)d[i] & 511u) << 21);
        }
        if (t[i] >= 2) {
            u32 b = (u32)s[i] >> 9;
            u32 slot = atomicAdd(&cur[b], 1u);
            u32 pos = gb[b] + slot;
            if (pos < ((b + 1u) << 14))
                tmpItems[pos] = (u32)d[i] | ((u32)(t[i] + 2) << 18) | (((u32)s[i] & 511u) << 21);
        }
    }
}

// ---- passB: per-(node,k) degree counts -> dinv (f32 + bf16) + kcnt[8N] (k=7 slot = pad) ----
__global__ __launch_bounds__(256)
void k_passB(const u32* __restrict__ tmpItems, const u32* __restrict__ bucketEnd,
             float* __restrict__ dinv, u16* __restrict__ dinv16,
             u32* __restrict__ kcnt, int N) {
    __shared__ u32 c[512 * 8];
    int b = blockIdx.x, tid = threadIdx.x;
    for (int i = tid; i < 4096; i += 256) c[i] = 0;
    __syncthreads();
    u32 beg = (u32)b << 14;
    u32 end = bucketEnd[b];
    u32 cap = beg + BCAP;
    if (end > cap) end = cap;
    for (u32 i = beg + tid; i < end; i += 256) {
        u32 it = tmpItems[i];
        atomicAdd(&c[(it >> 21) * 8 + ((it >> 18) & 7)], 1u);
    }
    __syncthreads();
    int nodeBase = b << 9;
    for (int l = tid; l < 512; l += 256) {
        int n = nodeBase + l;
        u32 tot = 0;
#pragma unroll
        for (int k = 0; k < 7; k++) {
            u32 g = c[l * 8 + k];
            tot += g;
            kcnt[(size_t)b * 4096 + l * 8 + k] = g;
            float v = rsqrtf(1.0f + (float)g);
            dinv[k * N + n] = v;
            dinv16[k * N + n] = f2bf(v);
        }
        kcnt[(size_t)b * 4096 + l * 8 + 7] = (8u - (tot & 7u)) & 7u;  // pad to 8-multiple
    }
}

// ---------------- scan over 8N elems, 8192/block, 256 blocks ----------------
__global__ __launch_bounds__(256)
void k_scan1(const u32* __restrict__ kcnt, u32* __restrict__ kofs, u32* __restrict__ bsums) {
    __shared__ u32 lds[256];
    int t = threadIdx.x;
    size_t base = (size_t)blockIdx.x * 8192 + (size_t)t * 32;
    u32 v[32];
    u32 s = 0;
    const uint4* src = (const uint4*)(kcnt + base);
#pragma unroll
    for (int q = 0; q < 8; q++) {
        uint4 c4 = src[q];
        v[q * 4 + 0] = s; s += c4.x;
        v[q * 4 + 1] = s; s += c4.y;
        v[q * 4 + 2] = s; s += c4.z;
        v[q * 4 + 3] = s; s += c4.w;
    }
    lds[t] = s; __syncthreads();
    for (int off = 1; off < 256; off <<= 1) {
        u32 x2 = (t >= off) ? lds[t - off] : 0u;
        __syncthreads();
        lds[t] += x2;
        __syncthreads();
    }
    u32 texcl = lds[t] - s;
    uint4* dst = (uint4*)(kofs + base);
#pragma unroll
    for (int q = 0; q < 8; q++) {
        uint4 o;
        o.x = v[q * 4 + 0] + texcl; o.y = v[q * 4 + 1] + texcl;
        o.z = v[q * 4 + 2] + texcl; o.w = v[q * 4 + 3] + texcl;
        dst[q] = o;
    }
    if (t == 255) bsums[blockIdx.x] = lds[255];
}

__global__ void k_scan2(const u32* __restrict__ bsums, u32* __restrict__ bexcl, int nb) {
    __shared__ u32 lds[256];
    int t = threadIdx.x;
    u32 v = (t < nb) ? bsums[t] : 0u;
    lds[t] = v; __syncthreads();
    for (int off = 1; off < 256; off <<= 1) {
        u32 x2 = (t >= off) ? lds[t - off] : 0u;
        __syncthreads();
        lds[t] += x2;
        __syncthreads();
    }
    if (t < nb) bexcl[t] = lds[t] - v;
}

__global__ __launch_bounds__(256)
void k_scan3(u32* __restrict__ kofs, const u32* __restrict__ bexcl,
             const u32* __restrict__ bsums, u32 M) {
    int t = threadIdx.x;
    size_t base = (size_t)blockIdx.x * 8192 + (size_t)t * 32;
    u32 add = bexcl[blockIdx.x];
    uint4* p4 = (uint4*)(kofs + base);
#pragma unroll
    for (int q = 0; q < 8; q++) {
        uint4 o = p4[q];
        o.x += add; o.y += add; o.z += add; o.w += add;
        p4[q] = o;
    }
    if (blockIdx.x == 255 && t == 255) kofs[M] = add + bsums[255];
}

// ---- passC-lite: scatter entries into final CSR positions (k-sorted, pre-scaled) ----
__global__ __launch_bounds__(256)
void k_passC(const u32* __restrict__ tmpItems, const u32* __restrict__ bucketEnd,
             const u32* __restrict__ kofs, u32* __restrict__ entries) {
    __shared__ u32 cur[4096];
    int b = blockIdx.x, tid = threadIdx.x;
    for (int i = tid; i < 4096; i += 256) cur[i] = kofs[(size_t)b * 4096 + i];
    __syncthreads();
    u32 beg = (u32)b << 14;
    u32 end = bucketEnd[b];
    u32 cap = beg + BCAP;
    if (end > cap) end = cap;
    for (u32 i = beg + tid; i < end; i += 256) {
        u32 it = tmpItems[i];
        u32 k = (it >> 18) & 7u;
        u32 src = it & 0x3FFFFu;
        u32 p = atomicAdd(&cur[(it >> 21) * 8 + k], 1u);
        entries[p] = (k << 28) | (src << 7);
    }
}

// ---- coef16 (coalesced) + depth-1 P/Q: one thread per (node,k) segment; k=7 = pad, skip ----
__global__ __launch_bounds__(256)
void k_coef_pq(const u32* __restrict__ entries, const u32* __restrict__ kofs,
               const u16* __restrict__ dinv16, const float* __restrict__ dinv,
               const float* __restrict__ x, u16* __restrict__ coef16,
               float* __restrict__ P, float* __restrict__ Q, int N) {
    int i = blockIdx.x * 256 + threadIdx.x;          // (node,k) slot, k = i&7
    int k = i & 7, n = i >> 3;
    if (k == 7) return;                              // pad slot
    u32 beg = kofs[i], end = kofs[i + 1];
    float sP = 0.f, sQ = 0.f;
    for (u32 p = beg; p < end; ++p) {
        u32 src = (entries[p] >> 7) & 0x3FFFFu;
        u16 cb = dinv16[(size_t)k * N + src];        // L2-resident (3.7 MB)
        coef16[p] = cb;
        float cf = bf2f(cb);
        sP += cf * x[src];
        sQ += cf;
    }
    float dk = dinv[k * N + n];
    float xn = x[n];
    P[i] = dk * (sP + dk * xn);
    Q[i] = dk * (sQ + dk);
}

// ================= small prep kernels =================
__global__ void k_bsum(Ptr7 b, float* __restrict__ bsum) {
    int d = threadIdx.x;
    float s = 0.f;
#pragma unroll
    for (int k = 0; k < 7; k++) s += b.p[k][d];
    bsum[d] = s;
}

__global__ void k_uv(const float* __restrict__ nW, const float* __restrict__ nb,
                     Ptr7 W, float* __restrict__ U, float* __restrict__ V) {
    int k = blockIdx.x, d = threadIdx.x;
    const float* Wk = W.p[k];
    float u = 0.f, v = 0.f;
#pragma unroll 8
    for (int j = 0; j < 64; j++) {
        float w = Wk[j * 64 + d];
        u += nW[j] * w;
        v += nb[j] * w;
    }
    U[k * 64 + d] = u;
    V[k * 64 + d] = v;
}

// pack W into MFMA B-fragment order
__global__ void k_packW(Ptr7 W, u16* __restrict__ Wp) {
    int k = blockIdx.x;
    int tid = threadIdx.x;                 // 512 threads
    int ks = tid >> 8, ct = (tid >> 6) & 3, l = tid & 63;
    const float* Wk = W.p[k];
    u16* dst = Wp + (((size_t)(k * 2 + ks) * 4 + ct) * 512 + l * 8);
    int row0 = ks * 32 + (l >> 4) * 8;
    int col = ct * 16 + (l & 15);
#pragma unroll
    for (int i = 0; i < 8; i++) dst[i] = f2bf(Wk[(row0 + i) * 64 + col]);
}

// ---------------- h1 = relu(P@U + Q@V + bsum) -> bf16 ----------------
__global__ __launch_bounds__(256)
void k_h1(const float* __restrict__ P, const float* __restrict__ Q,
          const float* __restrict__ U, const float* __restrict__ V,
          const float* __restrict__ bsum, u16* __restrict__ h1) {
    int i = blockIdx.x * 256 + threadIdx.x;
    int n = rfl(i >> 6);
    int d = i & 63;
    float acc = bsum[d];
#pragma unroll
    for (int k = 0; k < 7; k++)
        acc += P[n * 8 + k] * U[k * 64 + d] + Q[n * 8 + k] * V[k * 64 + d];
    h1[((size_t)n << 6) + d] = f2bf(fmaxf(acc, 0.f));
}

// ---------------- full gather (depths 2,3): scalar-load streams, no readlanes ----------------
__global__ __launch_bounds__(256)
void k_gather(const u16* __restrict__ h, const u32* __restrict__ entries,
              const u16* __restrict__ coef16, const u32* __restrict__ kofs,
              const float* __restrict__ dinv, u16* __restrict__ m, int N, int c0) {
    int lane = threadIdx.x & 63;
    int nl = blockIdx.x * 4 + (threadIdx.x >> 6);
    int n = c0 + nl;
    u32 beg = (u32)rfl((int)kofs[(size_t)n << 3]);          // 8-item aligned
    u32 end = (u32)rfl((int)kofs[((size_t)n << 3) + 7]);    // excludes pad slot
    float hv = bf2f(h[((size_t)n << 6) + lane]);
    float d0 = dinv[n],         d1 = dinv[N + n],     d2 = dinv[2 * N + n];
    float d3 = dinv[3 * N + n], d4 = dinv[4 * N + n], d5 = dinv[5 * N + n];
    float d6 = dinv[6 * N + n];
    float a0 = d0 * hv, a1 = d1 * hv, a2 = d2 * hv, a3 = d3 * hv;
    float a4 = d4 * hv, a5 = d5 * hv, a6 = d6 * hv;

    const u32* ep = entries + beg;                          // 32 B aligned
    const u32* cp = (const u32*)(coef16 + beg);             // 16 B aligned
    for (u32 base = beg; base < end; base += 8) {
        u32x8_t ev;
        u32x4_t cv;
        asm("s_load_dwordx8 %0, %2, 0x0\n\t"
            "s_load_dwordx4 %1, %3, 0x0\n\t"
            "s_waitcnt lgkmcnt(0)"
            : "=s"(ev), "=s"(cv)
            : "s"(ep), "s"(cp));
        ep += 8; cp += 4;
        int cnt = (int)(end - base);
        if (cnt > 8) cnt = 8;
#pragma unroll
        for (int j = 0; j < 8; j++) {
            if (j < cnt) {
                u32 pk = ev[j];
                u32 cw = cv[j >> 1];
                u32 cb = (j & 1) ? (cw >> 16) : (cw & 0xFFFFu);
                float cf = __uint_as_float(cb << 16);
                u32 off = (pk & 0x0FFFFFFFu) >> 1;          // element offset = src<<6
                float hval = bf2f(h[off + (u32)lane]);
                switch (pk >> 28) {
                    case 0: a0 = fmaf(cf, hval, a0); break;
                    case 1: a1 = fmaf(cf, hval, a1); break;
                    case 2: a2 = fmaf(cf, hval, a2); break;
                    case 3: a3 = fmaf(cf, hval, a3); break;
                    case 4: a4 = fmaf(cf, hval, a4); break;
                    case 5: a5 = fmaf(cf, hval, a5); break;
                    default: a6 = fmaf(cf, hval, a6); break;
                }
            }
        }
    }

    u16* mp = m + (size_t)nl * 448 + lane;
    __builtin_nontemporal_store(f2bf(d0 * a0), mp);
    __builtin_nontemporal_store(f2bf(d1 * a1), mp + 64);
    __builtin_nontemporal_store(f2bf(d2 * a2), mp + 128);
    __builtin_nontemporal_store(f2bf(d3 * a3), mp + 192);
    __builtin_nontemporal_store(f2bf(d4 * a4), mp + 256);
    __builtin_nontemporal_store(f2bf(d5 * a5), mp + 320);
    __builtin_nontemporal_store(f2bf(d6 * a6), mp + 384);
}

// ---------------- MFMA GEMM: [64,448]x[448,64] per block + bias + relu ----------------
__global__ __launch_bounds__(256)
void k_gemm(const u16* __restrict__ m, const u16* __restrict__ Wp,
            const float* __restrict__ bsum, u16* __restrict__ hout, int c0) {
    int tid = threadIdx.x;
    int w = tid >> 6, l = tid & 63;
    int nb = blockIdx.x << 6;                            // chunk-local node base
    const u16* arow = m + (size_t)(nb + (w << 4) + (l & 15)) * 448 + ((l >> 4) << 3);
    const u16* bp = Wp + (size_t)l * 8;
    f32x4 acc0 = {0,0,0,0}, acc1 = {0,0,0,0}, acc2 = {0,0,0,0}, acc3 = {0,0,0,0};
#pragma unroll
    for (int kk = 0; kk < 14; kk++) {
        bf16x8 a  = __builtin_nontemporal_load((const bf16x8*)(arow + kk * 32));
        bf16x8 b0 = *(const bf16x8*)(bp + (size_t)(kk * 4 + 0) * 512);
        bf16x8 b1 = *(const bf16x8*)(bp + (size_t)(kk * 4 + 1) * 512);
        bf16x8 b2 = *(const bf16x8*)(bp + (size_t)(kk * 4 + 2) * 512);
        bf16x8 b3 = *(const bf16x8*)(bp + (size_t)(kk * 4 + 3) * 512);
        acc0 = __builtin_amdgcn_mfma_f32_16x16x32_bf16(a, b0, acc0, 0, 0, 0);
        acc1 = __builtin_amdgcn_mfma_f32_16x16x32_bf16(a, b1, acc1, 0, 0, 0);
        acc2 = __builtin_amdgcn_mfma_f32_16x16x32_bf16(a, b2, acc2, 0, 0, 0);
        acc3 = __builtin_amdgcn_mfma_f32_16x16x32_bf16(a, b3, acc3, 0, 0, 0);
    }
    int rl = (l >> 4) << 2, cl = l & 15;
    int rowg = c0 + nb + (w << 4) + rl;
    f32x4 accs[4] = {acc0, acc1, acc2, acc3};
#pragma unroll
    for (int ct = 0; ct < 4; ct++) {
        int col = ct * 16 + cl;
        float bv = bsum[col];
#pragma unroll
        for (int reg = 0; reg < 4; reg++) {
            float vv = fmaxf(accs[ct][reg] + bv, 0.f);
            hout[(size_t)(rowg + reg) * 64 + col] = f2bf(vv);
        }
    }
}

// ---------------- pooling + 2-layer MLP head (bf16 h) ----------------
__global__ __launch_bounds__(256)
void k_head(const u16* __restrict__ h, const float* __restrict__ w1,
            const float* __restrict__ b1, const float* __restrict__ w2,
            const float* __restrict__ b2, float* __restrict__ out) {
    __shared__ float gmax[4][64];
    __shared__ float gl[64];
    __shared__ float t1p[4][64];
    int b = blockIdx.x;
    int tid = threadIdx.x;
    int d = tid & 63, rg = tid >> 6;
    const u16* hb = h + (size_t)b * 64 * 64;
    float pm = -1e30f;
#pragma unroll
    for (int i = 0; i < 16; i++) pm = fmaxf(pm, bf2f(hb[(rg * 16 + i) * 64 + d]));
    gmax[rg][d] = pm; __syncthreads();
    if (rg == 0) gl[d] = fmaxf(fmaxf(gmax[0][d], gmax[1][d]), fmaxf(gmax[2][d], gmax[3][d]));
    __syncthreads();
    float s = 0.f;
#pragma unroll
    for (int i = 0; i < 16; i++) { int dd = rg * 16 + i; s += gl[dd] * w1[dd * 64 + d]; }
    t1p[rg][d] = s; __syncthreads();
    if (rg == 0) {
        float t1 = fmaxf(t1p[0][d] + t1p[1][d] + t1p[2][d] + t1p[3][d] + b1[d], 0.f);
        float v = t1 * w2[d];
        for (int off = 32; off; off >>= 1) v += __shfl_down(v, off, 64);
        if (d == 0) out[b] = v + b2[0];
    }
}

extern "C" void kernel_launch(void* const* d_in, const int* in_sizes, int n_in,
                              void* d_out, int out_size, void* d_ws, size_t ws_size,
                              hipStream_t stream) {
    const float* x     = (const float*)d_in[0];
    const int*   ei    = (const int*)d_in[1];
    const int*   ty    = (const int*)d_in[2];
    const float* nodeW = (const float*)d_in[3];
    const float* nodeb = (const float*)d_in[4];
    const float* out1W = (const float*)d_in[5];
    const float* out1b = (const float*)d_in[6];
    const float* out2W = (const float*)d_in[7];
    const float* out2b = (const float*)d_in[8];

    Ptr7 W, B;
    W.p[0] = (const float*)d_in[9];  B.p[0] = (const float*)d_in[10];   // W1
    W.p[1] = (const float*)d_in[11]; B.p[1] = (const float*)d_in[12];   // W2
    W.p[2] = (const float*)d_in[13]; B.p[2] = (const float*)d_in[14];   // W3
    W.p[3] = (const float*)d_in[15]; B.p[3] = (const float*)d_in[16];   // W4
    W.p[4] = (const float*)d_in[17]; B.p[4] = (const float*)d_in[18];   // W2b
    W.p[5] = (const float*)d_in[19]; B.p[5] = (const float*)d_in[20];   // W3b
    W.p[6] = (const float*)d_in[21]; B.p[6] = (const float*)d_in[22];   // W4b

    const int N = in_sizes[0];       // 262144
    const int E = in_sizes[2];       // 4194304

    char* p = (char*)d_ws;
    auto carve = [&](size_t bytes) { void* r = (void*)p; p += (bytes + 255) & ~(size_t)255; return r; };
    u16*   hA       = (u16*)carve((size_t)N * 64 * 2);
    u16*   hB       = (u16*)carve((size_t)N * 64 * 2);
    u32*   entries  = (u32*)carve((size_t)2 * E * 4 + 256);   // padded total < 2E
    u16*   coef16   = (u16*)carve((size_t)2 * E * 2 + 128);
    float* dinv     = (float*)carve((size_t)7 * N * 4);
    u16*   dinv16   = (u16*)carve((size_t)7 * N * 2);
    u32*   kcnt     = (u32*)carve((size_t)8 * N * 4);
    u32*   kofs     = (u32*)carve(((size_t)8 * N + 1) * 4);
    float* P        = (float*)carve((size_t)N * 8 * 4);
    float* Q        = (float*)carve((size_t)N * 8 * 4);
    float* U        = (float*)carve(7 * 64 * 4);
    float* V        = (float*)carve(7 * 64 * 4);
    float* bsum     = (float*)carve(256);
    u16*   Wp       = (u16*)carve((size_t)7 * 2 * 4 * 512 * 2);
    u32*   gcursor  = (u32*)carve(512 * 4);
    u32*   bsums    = (u32*)carve(1024);
    u32*   bexcl    = (u32*)carve(1024);
    size_t used = (size_t)(p - (char*)d_ws);
    size_t avail = (ws_size > used) ? (ws_size - used) : 0;
    // union region: tmpItems (512*BCAP u32 = 33.5 MB, dead after passC) aliases m chunk
    u32*   tmpItems = (u32*)p;
    u16*   m        = (u16*)p;
    size_t chunkNodes = (avail / (448 * 2)) & ~(size_t)63;
    if (chunkNodes < 64) chunkNodes = 64;
    if (chunkNodes > 131072) chunkNodes = 131072;
    if (chunkNodes > (size_t)N) chunkNodes = (size_t)N;
    (void)n_in; (void)out_size;

    // ---- bucketed CSR build (fixed-capacity buckets; single-pass register passA) ----
    k_init_cur<<<2, 256, 0, stream>>>(gcursor);
    k_passA<<<(E + 4095) / 4096, 256, 0, stream>>>(ei, ty, E, gcursor, tmpItems);
    k_passB<<<512, 256, 0, stream>>>(tmpItems, gcursor, dinv, dinv16, kcnt, N);
    k_scan1<<<256, 256, 0, stream>>>(kcnt, kofs, bsums);
    k_scan2<<<1, 256, 0, stream>>>(bsums, bexcl, 256);
    k_scan3<<<256, 256, 0, stream>>>(kofs, bexcl, bsums, (u32)8 * N);
    k_passC<<<512, 256, 0, stream>>>(tmpItems, gcursor, kofs, entries);
    k_coef_pq<<<(8 * N) / 256, 256, 0, stream>>>(entries, kofs, dinv16, dinv, x,
                                                 coef16, P, Q, N);

    k_bsum<<<1, 64, 0, stream>>>(B, bsum);
    k_uv<<<7, 64, 0, stream>>>(nodeW, nodeb, W, U, V);
    k_packW<<<7, 512, 0, stream>>>(W, Wp);

    // depth 1 via rank-2 shortcut (P/Q computed in k_coef_pq)
    k_h1<<<(N * 64) / 256, 256, 0, stream>>>(P, Q, U, V, bsum, hA);

    // depths 2,3: separate high-occupancy gather + MFMA GEMM, chunked
    u16* hcur = hA;
    u16* hnext = hB;
    for (int depth = 0; depth < 2; depth++) {
        for (int c0 = 0; c0 < N; c0 += (int)chunkNodes) {
            int cn = (int)(((size_t)(N - c0) < chunkNodes) ? (size_t)(N - c0) : chunkNodes);
            k_gather<<<cn / 4, 256, 0, stream>>>(hcur, entries, coef16, kofs, dinv, m, N, c0);
            k_gemm<<<cn / 64, 256, 0, stream>>>(m, Wp, bsum, hnext, c0);
        }
        u16* t = hcur; hcur = hnext; hnext = t;
    }

    k_head<<<N / 64, 256, 0, stream>>>(hcur, out1W, out1b, out2W, out2b, (float*)d_out);
}

// Round 13
// 787.130 us; speedup vs baseline: 1.5992x; 1.5992x over previous
//
#include <hip/hip_runtime.h>
#include <stdint.h>

typedef unsigned int u32;
typedef unsigned short u16;
typedef __attribute__((ext_vector_type(8))) short bf16x8;
typedef __attribute__((ext_vector_type(4))) float f32x4;

#define BCAP 16384u   // per-bucket item capacity (mean fill ~11.5K, 46 sigma margin)

struct Ptr7 { const float* p[7]; };

__device__ __forceinline__ int rfl(int v) { return __builtin_amdgcn_readfirstlane(v); }
__device__ __forceinline__ u16 f2bf(float f) {
    u32 u = __float_as_uint(f);
    u32 r = (u + 0x7FFFu + ((u >> 16) & 1u)) >> 16;
    return (u16)r;
}
__device__ __forceinline__ float bf2f(u16 h) { return __uint_as_float((u32)h << 16); }

// ================= bucketed CSR build, 512 fixed-capacity buckets of 512 nodes ===========
// tmp item = src(18b) | k(3b)<<18 | dstlocal(9b)<<21 ; bucket = target >> 9
// final entry = (k<<28) | (src<<7)

__global__ void k_init_cur(u32* __restrict__ g) {
    int i = blockIdx.x * 256 + threadIdx.x;
    if (i < 512) g[i] = (u32)i << 14;     // b * BCAP
}

// single-pass: 16 edges/thread held in registers (one vmcnt batch), then hist/alloc/scatter
__global__ __launch_bounds__(256)
void k_passA(const int* __restrict__ ei, const int* __restrict__ ty, int E,
             u32* __restrict__ gcursor, u32* __restrict__ tmpItems) {
    __shared__ u32 hist[512], gb[512], cur[512];
    int tid = threadIdx.x;
    int e0 = blockIdx.x * 4096;
    int s[16], d[16], t[16];
#pragma unroll
    for (int i = 0; i < 16; i++) {
        int e = e0 + i * 256 + tid;
        if (e < E) { s[i] = ei[e]; d[i] = ei[E + e]; t[i] = ty[e]; }
        else t[i] = 0;
    }
    hist[tid] = 0; hist[tid + 256] = 0;
    __syncthreads();
#pragma unroll
    for (int i = 0; i < 16; i++) {
        if (t[i] >= 1) atomicAdd(&hist[(u32)d[i] >> 9], 1u);
        if (t[i] >= 2) atomicAdd(&hist[(u32)s[i] >> 9], 1u);
    }
    __syncthreads();
    u32 h0 = hist[tid], h1 = hist[tid + 256];
    gb[tid] = h0 ? atomicAdd(&gcursor[tid], h0) : 0u;
    gb[tid + 256] = h1 ? atomicAdd(&gcursor[tid + 256], h1) : 0u;
    cur[tid] = 0; cur[tid + 256] = 0;
    __syncthreads();
#pragma unroll
    for (int i = 0; i < 16; i++) {
        if (t[i] >= 1) {
            u32 b = (u32)d[i] >> 9;
            u32 slot = atomicAdd(&cur[b], 1u);
            u32 pos = gb[b] + slot;
            if (pos < ((b + 1u) << 14))
                tmpItems[pos] = (u32)s[i] | ((u32)(t[i] - 1) << 18) | (((u32)d[i] & 511u) << 21);
        }
        if (t[i] >= 2) {
            u32 b = (u32)s[i] >> 9;
            u32 slot = atomicAdd(&cur[b], 1u);
            u32 pos = gb[b] + slot;
            if (pos < ((b + 1u) << 14))
                tmpItems[pos] = (u32)d[i] | ((u32)(t[i] + 2) << 18) | (((u32)s[i] & 511u) << 21);
        }
    }
}

// ---- passB: per-(node,k) degree counts -> dinv (f32 + bf16) + kcnt[8N] ----
__global__ __launch_bounds__(256)
void k_passB(const u32* __restrict__ tmpItems, const u32* __restrict__ bucketEnd,
             float* __restrict__ dinv, u16* __restrict__ dinv16,
             u32* __restrict__ kcnt, int N) {
    __shared__ u32 c[512 * 8];
    int b = blockIdx.x, tid = threadIdx.x;
    for (int i = tid; i < 4096; i += 256) c[i] = 0;
    __syncthreads();
    u32 beg = (u32)b << 14;
    u32 end = bucketEnd[b];
    u32 cap = beg + BCAP;
    if (end > cap) end = cap;
    for (u32 i = beg + tid; i < end; i += 256) {
        u32 it = tmpItems[i];
        atomicAdd(&c[(it >> 21) * 8 + ((it >> 18) & 7)], 1u);
    }
    __syncthreads();
    int nodeBase = b << 9;
    for (int i = tid; i < 4096; i += 256) kcnt[(size_t)b * 4096 + i] = c[i];
    for (int l = tid; l < 512; l += 256) {
        int n = nodeBase + l;
#pragma unroll
        for (int k = 0; k < 7; k++) {
            float v = rsqrtf(1.0f + (float)c[l * 8 + k]);
            dinv[k * N + n] = v;
            dinv16[k * N + n] = f2bf(v);
        }
    }
}

// ---------------- scan over 8N elems, 8192/block, 256 blocks ----------------
__global__ __launch_bounds__(256)
void k_scan1(const u32* __restrict__ kcnt, u32* __restrict__ kofs, u32* __restrict__ bsums) {
    __shared__ u32 lds[256];
    int t = threadIdx.x;
    size_t base = (size_t)blockIdx.x * 8192 + (size_t)t * 32;
    u32 v[32];
    u32 s = 0;
    const uint4* src = (const uint4*)(kcnt + base);
#pragma unroll
    for (int q = 0; q < 8; q++) {
        uint4 c4 = src[q];
        v[q * 4 + 0] = s; s += c4.x;
        v[q * 4 + 1] = s; s += c4.y;
        v[q * 4 + 2] = s; s += c4.z;
        v[q * 4 + 3] = s; s += c4.w;
    }
    lds[t] = s; __syncthreads();
    for (int off = 1; off < 256; off <<= 1) {
        u32 x2 = (t >= off) ? lds[t - off] : 0u;
        __syncthreads();
        lds[t] += x2;
        __syncthreads();
    }
    u32 texcl = lds[t] - s;
    uint4* dst = (uint4*)(kofs + base);
#pragma unroll
    for (int q = 0; q < 8; q++) {
        uint4 o;
        o.x = v[q * 4 + 0] + texcl; o.y = v[q * 4 + 1] + texcl;
        o.z = v[q * 4 + 2] + texcl; o.w = v[q * 4 + 3] + texcl;
        dst[q] = o;
    }
    if (t == 255) bsums[blockIdx.x] = lds[255];
}

__global__ void k_scan2(const u32* __restrict__ bsums, u32* __restrict__ bexcl, int nb) {
    __shared__ u32 lds[256];
    int t = threadIdx.x;
    u32 v = (t < nb) ? bsums[t] : 0u;
    lds[t] = v; __syncthreads();
    for (int off = 1; off < 256; off <<= 1) {
        u32 x2 = (t >= off) ? lds[t - off] : 0u;
        __syncthreads();
        lds[t] += x2;
        __syncthreads();
    }
    if (t < nb) bexcl[t] = lds[t] - v;
}

__global__ __launch_bounds__(256)
void k_scan3(u32* __restrict__ kofs, const u32* __restrict__ bexcl,
             const u32* __restrict__ bsums, u32 M) {
    int t = threadIdx.x;
    size_t base = (size_t)blockIdx.x * 8192 + (size_t)t * 32;
    u32 add = bexcl[blockIdx.x];
    uint4* p4 = (uint4*)(kofs + base);
#pragma unroll
    for (int q = 0; q < 8; q++) {
        uint4 o = p4[q];
        o.x += add; o.y += add; o.z += add; o.w += add;
        p4[q] = o;
    }
    if (blockIdx.x == 255 && t == 255) kofs[M] = add + bsums[255];
}

// ---- passC-lite: scatter entries into final CSR positions (k-sorted, pre-scaled) ----
__global__ __launch_bounds__(256)
void k_passC(const u32* __restrict__ tmpItems, const u32* __restrict__ bucketEnd,
             const u32* __restrict__ kofs, u32* __restrict__ entries) {
    __shared__ u32 cur[4096];
    int b = blockIdx.x, tid = threadIdx.x;
    for (int i = tid; i < 4096; i += 256) cur[i] = kofs[(size_t)b * 4096 + i];
    __syncthreads();
    u32 beg = (u32)b << 14;
    u32 end = bucketEnd[b];
    u32 cap = beg + BCAP;
    if (end > cap) end = cap;
    for (u32 i = beg + tid; i < end; i += 256) {
        u32 it = tmpItems[i];
        u32 k = (it >> 18) & 7u;
        u32 src = it & 0x3FFFFu;
        u32 p = atomicAdd(&cur[(it >> 21) * 8 + k], 1u);
        entries[p] = (k << 28) | (src << 7);
    }
}

// ---- coef16 (coalesced) + depth-1 P/Q: one thread per (node,k) segment ----
__global__ __launch_bounds__(256)
void k_coef_pq(const u32* __restrict__ entries, const u32* __restrict__ kofs,
               const u16* __restrict__ dinv16, const float* __restrict__ dinv,
               const float* __restrict__ x, u16* __restrict__ coef16,
               float* __restrict__ P, float* __restrict__ Q, int N) {
    int i = blockIdx.x * 256 + threadIdx.x;          // (node,k) slot, k = i&7
    int k = i & 7, n = i >> 3;
    if (k == 7) return;                              // unused slot
    u32 beg = kofs[i], end = kofs[i + 1];
    float sP = 0.f, sQ = 0.f;
    for (u32 p = beg; p < end; ++p) {
        u32 src = (entries[p] >> 7) & 0x3FFFFu;
        u16 cb = dinv16[(size_t)k * N + src];        // L2-resident (3.7 MB)
        coef16[p] = cb;
        float cf = bf2f(cb);
        sP += cf * x[src];
        sQ += cf;
    }
    float dk = dinv[k * N + n];
    float xn = x[n];
    P[i] = dk * (sP + dk * xn);
    Q[i] = dk * (sQ + dk);
}

// ================= small prep kernels =================
__global__ void k_bsum(Ptr7 b, float* __restrict__ bsum) {
    int d = threadIdx.x;
    float s = 0.f;
#pragma unroll
    for (int k = 0; k < 7; k++) s += b.p[k][d];
    bsum[d] = s;
}

__global__ void k_uv(const float* __restrict__ nW, const float* __restrict__ nb,
                     Ptr7 W, float* __restrict__ U, float* __restrict__ V) {
    int k = blockIdx.x, d = threadIdx.x;
    const float* Wk = W.p[k];
    float u = 0.f, v = 0.f;
#pragma unroll 8
    for (int j = 0; j < 64; j++) {
        float w = Wk[j * 64 + d];
        u += nW[j] * w;
        v += nb[j] * w;
    }
    U[k * 64 + d] = u;
    V[k * 64 + d] = v;
}

// pack W into MFMA B-fragment order
__global__ void k_packW(Ptr7 W, u16* __restrict__ Wp) {
    int k = blockIdx.x;
    int tid = threadIdx.x;                 // 512 threads
    int ks = tid >> 8, ct = (tid >> 6) & 3, l = tid & 63;
    const float* Wk = W.p[k];
    u16* dst = Wp + (((size_t)(k * 2 + ks) * 4 + ct) * 512 + l * 8);
    int row0 = ks * 32 + (l >> 4) * 8;
    int col = ct * 16 + (l & 15);
#pragma unroll
    for (int i = 0; i < 8; i++) dst[i] = f2bf(Wk[(row0 + i) * 64 + col]);
}

// ---------------- h1 = relu(P@U + Q@V + bsum) -> bf16 ----------------
__global__ __launch_bounds__(256)
void k_h1(const float* __restrict__ P, const float* __restrict__ Q,
          const float* __restrict__ U, const float* __restrict__ V,
          const float* __restrict__ bsum, u16* __restrict__ h1) {
    int i = blockIdx.x * 256 + threadIdx.x;
    int n = rfl(i >> 6);
    int d = i & 63;
    float acc = bsum[d];
#pragma unroll
    for (int k = 0; k < 7; k++)
        acc += P[n * 8 + k] * U[k * 64 + d] + Q[n * 8 + k] * V[k * 64 + d];
    h1[((size_t)n << 6) + d] = f2bf(fmaxf(acc, 0.f));
}

// ======== fused gather + MFMA GEMM (depths 2,3): 512 thr / 32 nodes / 29 KB LDS ========
#define GACC(PK, CB, HV)                                             \
    {                                                                \
        float cf_ = __uint_as_float((u32)(CB) << 16);                \
        switch ((PK) >> 28) {                                        \
            case 0: a0 = fmaf(cf_, (HV), a0); break;                 \
            case 1: a1 = fmaf(cf_, (HV), a1); break;                 \
            case 2: a2 = fmaf(cf_, (HV), a2); break;                 \
            case 3: a3 = fmaf(cf_, (HV), a3); break;                 \
            case 4: a4 = fmaf(cf_, (HV), a4); break;                 \
            case 5: a5 = fmaf(cf_, (HV), a5); break;                 \
            default: a6 = fmaf(cf_, (HV), a6); break;                \
        }                                                            \
    }
#define HLOAD(PK) bf2f(h[(((PK) & 0x0FFFFFFFu) >> 1) + (u32)lane])

__global__ __launch_bounds__(512, 8)
void k_fused(const u16* __restrict__ h, const u32* __restrict__ entries,
             const u16* __restrict__ coef16, const u32* __restrict__ kofs,
             const float* __restrict__ dinv, const u16* __restrict__ Wp,
             const float* __restrict__ bsum, u16* __restrict__ hout, int N) {
    __shared__ u16 mlds[32 * 456];      // [node][456] (448 + 8 pad: conflict-free banks)
    int tid = threadIdx.x;
    int w = tid >> 6, lane = tid & 63;
    int nb = blockIdx.x << 5;           // 32 nodes per block

    // ---- phase 1: each of 8 waves gathers 4 nodes (round-11 inner loop) ----
    for (int rr = 0; rr < 4; ++rr) {
        int nn = (w << 2) + rr;
        int n = nb + nn;
        u32 beg = (u32)rfl((int)kofs[(size_t)n << 3]);
        u32 end = (u32)rfl((int)kofs[((size_t)n << 3) + 7]);
        float hv = bf2f(h[((size_t)n << 6) + lane]);
        float d0 = dinv[n],         d1 = dinv[N + n],     d2 = dinv[2 * N + n];
        float d3 = dinv[3 * N + n], d4 = dinv[4 * N + n], d5 = dinv[5 * N + n];
        float d6 = dinv[6 * N + n];
        float a0 = d0 * hv, a1 = d1 * hv, a2 = d2 * hv, a3 = d3 * hv;
        float a4 = d4 * hv, a5 = d5 * hv, a6 = d6 * hv;

        u32 base = beg;
        u32 e = 0, cfw = 0;
        if (base + (u32)lane < end) {
            e = __builtin_nontemporal_load(&entries[base + lane]);
            cfw = (u32)__builtin_nontemporal_load(&coef16[base + lane]);
        }
        while (base < end) {
            u32 rem = end - base;
            int cnt = (rem < 64u) ? (int)rem : 64;
            u32 nb2 = base + 64;
            u32 en = 0, cfn = 0;
            if (nb2 + (u32)lane < end) {            // prefetch next batch
                en = __builtin_nontemporal_load(&entries[nb2 + lane]);
                cfn = (u32)__builtin_nontemporal_load(&coef16[nb2 + lane]);
            }
            int j = 0;
            for (; j + 8 <= cnt; j += 8) {
                u32 pk0 = (u32)__builtin_amdgcn_readlane((int)e, j + 0);
                u32 pk1 = (u32)__builtin_amdgcn_readlane((int)e, j + 1);
                u32 pk2 = (u32)__builtin_amdgcn_readlane((int)e, j + 2);
                u32 pk3 = (u32)__builtin_amdgcn_readlane((int)e, j + 3);
                u32 pk4 = (u32)__builtin_amdgcn_readlane((int)e, j + 4);
                u32 pk5 = (u32)__builtin_amdgcn_readlane((int)e, j + 5);
                u32 pk6 = (u32)__builtin_amdgcn_readlane((int)e, j + 6);
                u32 pk7 = (u32)__builtin_amdgcn_readlane((int)e, j + 7);
                u32 cb0 = (u32)__builtin_amdgcn_readlane((int)cfw, j + 0);
                u32 cb1 = (u32)__builtin_amdgcn_readlane((int)cfw, j + 1);
                u32 cb2 = (u32)__builtin_amdgcn_readlane((int)cfw, j + 2);
                u32 cb3 = (u32)__builtin_amdgcn_readlane((int)cfw, j + 3);
                u32 cb4 = (u32)__builtin_amdgcn_readlane((int)cfw, j + 4);
                u32 cb5 = (u32)__builtin_amdgcn_readlane((int)cfw, j + 5);
                u32 cb6 = (u32)__builtin_amdgcn_readlane((int)cfw, j + 6);
                u32 cb7 = (u32)__builtin_amdgcn_readlane((int)cfw, j + 7);
                float h0 = HLOAD(pk0);
                float h1v = HLOAD(pk1);
                float h2v = HLOAD(pk2);
                float h3v = HLOAD(pk3);
                float h4v = HLOAD(pk4);
                float h5v = HLOAD(pk5);
                float h6v = HLOAD(pk6);
                float h7v = HLOAD(pk7);
                GACC(pk0, cb0, h0)
                GACC(pk1, cb1, h1v)
                GACC(pk2, cb2, h2v)
                GACC(pk3, cb3, h3v)
                GACC(pk4, cb4, h4v)
                GACC(pk5, cb5, h5v)
                GACC(pk6, cb6, h6v)
                GACC(pk7, cb7, h7v)
            }
            for (; j < cnt; ++j) {
                u32 pk = (u32)__builtin_amdgcn_readlane((int)e, j);
                u32 cb = (u32)__builtin_amdgcn_readlane((int)cfw, j);
                float hval = HLOAD(pk);
                GACC(pk, cb, hval)
            }
            e = en; cfw = cfn; base = nb2;
        }

        u16* mp = mlds + nn * 456 + lane;
        mp[0]   = f2bf(d0 * a0); mp[64]  = f2bf(d1 * a1); mp[128] = f2bf(d2 * a2);
        mp[192] = f2bf(d3 * a3); mp[256] = f2bf(d4 * a4); mp[320] = f2bf(d5 * a5);
        mp[384] = f2bf(d6 * a6);
    }
    __syncthreads();

    // ---- phase 2: [32,448] x [448,64] MFMA GEMM + bias + relu ----
    int rg = w >> 2, cq = w & 3;        // 8 waves: 2 row-groups x 4 col-quads
    const u16* bp = Wp + (size_t)cq * 512 + (size_t)lane * 8;
    const u16* arow = mlds + (rg * 16 + (lane & 15)) * 456 + ((lane >> 4) << 3);
    f32x4 acc = {0, 0, 0, 0};
#pragma unroll
    for (int kk = 0; kk < 14; kk++) {
        bf16x8 a = *(const bf16x8*)(arow + kk * 32);
        bf16x8 b = *(const bf16x8*)(bp + (size_t)kk * 4 * 512);
        acc = __builtin_amdgcn_mfma_f32_16x16x32_bf16(a, b, acc, 0, 0, 0);
    }
    int col = cq * 16 + (lane & 15);
    int row0 = nb + rg * 16 + ((lane >> 4) << 2);
    float bv = bsum[col];
#pragma unroll
    for (int reg = 0; reg < 4; reg++) {
        float vv = fmaxf(acc[reg] + bv, 0.f);
        hout[(size_t)(row0 + reg) * 64 + col] = f2bf(vv);
    }
}

// ---------------- pooling + 2-layer MLP head (bf16 h) ----------------
__global__ __launch_bounds__(256)
void k_head(const u16* __restrict__ h, const float* __restrict__ w1,
            const float* __restrict__ b1, const float* __restrict__ w2,
            const float* __restrict__ b2, float* __restrict__ out) {
    __shared__ float gmax[4][64];
    __shared__ float gl[64];
    __shared__ float t1p[4][64];
    int b = blockIdx.x;
    int tid = threadIdx.x;
    int d = tid & 63, rg = tid >> 6;
    const u16* hb = h + (size_t)b * 64 * 64;
    float pm = -1e30f;
#pragma unroll
    for (int i = 0; i < 16; i++) pm = fmaxf(pm, bf2f(hb[(rg * 16 + i) * 64 + d]));
    gmax[rg][d] = pm; __syncthreads();
    if (rg == 0) gl[d] = fmaxf(fmaxf(gmax[0][d], gmax[1][d]), fmaxf(gmax[2][d], gmax[3][d]));
    __syncthreads();
    float s = 0.f;
#pragma unroll
    for (int i = 0; i < 16; i++) { int dd = rg * 16 + i; s += gl[dd] * w1[dd * 64 + d]; }
    t1p[rg][d] = s; __syncthreads();
    if (rg == 0) {
        float t1 = fmaxf(t1p[0][d] + t1p[1][d] + t1p[2][d] + t1p[3][d] + b1[d], 0.f);
        float v = t1 * w2[d];
        for (int off = 32; off; off >>= 1) v += __shfl_down(v, off, 64);
        if (d == 0) out[b] = v + b2[0];
    }
}

extern "C" void kernel_launch(void* const* d_in, const int* in_sizes, int n_in,
                              void* d_out, int out_size, void* d_ws, size_t ws_size,
                              hipStream_t stream) {
    const float* x     = (const float*)d_in[0];
    const int*   ei    = (const int*)d_in[1];
    const int*   ty    = (const int*)d_in[2];
    const float* nodeW = (const float*)d_in[3];
    const float* nodeb = (const float*)d_in[4];
    const float* out1W = (const float*)d_in[5];
    const float* out1b = (const float*)d_in[6];
    const float* out2W = (const float*)d_in[7];
    const float* out2b = (const float*)d_in[8];

    Ptr7 W, B;
    W.p[0] = (const float*)d_in[9];  B.p[0] = (const float*)d_in[10];   // W1
    W.p[1] = (const float*)d_in[11]; B.p[1] = (const float*)d_in[12];   // W2
    W.p[2] = (const float*)d_in[13]; B.p[2] = (const float*)d_in[14];   // W3
    W.p[3] = (const float*)d_in[15]; B.p[3] = (const float*)d_in[16];   // W4
    W.p[4] = (const float*)d_in[17]; B.p[4] = (const float*)d_in[18];   // W2b
    W.p[5] = (const float*)d_in[19]; B.p[5] = (const float*)d_in[20];   // W3b
    W.p[6] = (const float*)d_in[21]; B.p[6] = (const float*)d_in[22];   // W4b

    const int N = in_sizes[0];       // 262144
    const int E = in_sizes[2];       // 4194304

    char* p = (char*)d_ws;
    auto carve = [&](size_t bytes) { void* r = (void*)p; p += (bytes + 255) & ~(size_t)255; return r; };
    u16*   hA       = (u16*)carve((size_t)N * 64 * 2);
    u16*   hB       = (u16*)carve((size_t)N * 64 * 2);
    u32*   entries  = (u32*)carve((size_t)2 * E * 4 + 256);
    u16*   coef16   = (u16*)carve((size_t)2 * E * 2 + 128);
    float* dinv     = (float*)carve((size_t)7 * N * 4);
    u16*   dinv16   = (u16*)carve((size_t)7 * N * 2);
    u32*   kcnt     = (u32*)carve((size_t)8 * N * 4);
    u32*   kofs     = (u32*)carve(((size_t)8 * N + 1) * 4);
    float* P        = (float*)carve((size_t)N * 8 * 4);
    float* Q        = (float*)carve((size_t)N * 8 * 4);
    float* U        = (float*)carve(7 * 64 * 4);
    float* V        = (float*)carve(7 * 64 * 4);
    float* bsum     = (float*)carve(256);
    u16*   Wp       = (u16*)carve((size_t)7 * 2 * 4 * 512 * 2);
    u32*   gcursor  = (u32*)carve(512 * 4);
    u32*   bsums    = (u32*)carve(1024);
    u32*   bexcl    = (u32*)carve(1024);
    // tmpItems (512*BCAP u32 = 33.5 MB, dead after passC) lives in the free tail
    u32*   tmpItems = (u32*)p;
    (void)n_in; (void)out_size; (void)ws_size;

    // ---- bucketed CSR build ----
    k_init_cur<<<2, 256, 0, stream>>>(gcursor);
    k_passA<<<(E + 4095) / 4096, 256, 0, stream>>>(ei, ty, E, gcursor, tmpItems);
    k_passB<<<512, 256, 0, stream>>>(tmpItems, gcursor, dinv, dinv16, kcnt, N);
    k_scan1<<<256, 256, 0, stream>>>(kcnt, kofs, bsums);
    k_scan2<<<1, 256, 0, stream>>>(bsums, bexcl, 256);
    k_scan3<<<256, 256, 0, stream>>>(kofs, bexcl, bsums, (u32)8 * N);
    k_passC<<<512, 256, 0, stream>>>(tmpItems, gcursor, kofs, entries);
    k_coef_pq<<<(8 * N) / 256, 256, 0, stream>>>(entries, kofs, dinv16, dinv, x,
                                                 coef16, P, Q, N);

    k_bsum<<<1, 64, 0, stream>>>(B, bsum);
    k_uv<<<7, 64, 0, stream>>>(nodeW, nodeb, W, U, V);
    k_packW<<<7, 512, 0, stream>>>(W, Wp);

    // depth 1 via rank-2 shortcut (P/Q computed in k_coef_pq)
    k_h1<<<(N * 64) / 256, 256, 0, stream>>>(P, Q, U, V, bsum, hA);

    // depths 2,3: fused gather + MFMA GEMM (full occupancy: 512 thr, 29 KB LDS)
    k_fused<<<N / 32, 512, 0, stream>>>(hA, entries, coef16, kofs, dinv, Wp, bsum, hB, N);
    k_fused<<<N / 32, 512, 0, stream>>>(hB, entries, coef16, kofs, dinv, Wp, bsum, hA, N);

    k_head<<<N / 64, 256, 0, stream>>>(hA, out1W, out1b, out2W, out2b, (float*)d_out);
}

// Round 14
// 779.293 us; speedup vs baseline: 1.6153x; 1.0101x over previous
//
#include <hip/hip_runtime.h>
#include <stdint.h>

typedef unsigned int u32;
typedef unsigned short u16;
typedef __attribute__((ext_vector_type(8))) short bf16x8;
typedef __attribute__((ext_vector_type(4))) float f32x4;

#define BCAP 16384u   // per-bucket item capacity (mean fill ~11.5K, 46 sigma margin)

struct Ptr7 { const float* p[7]; };

__device__ __forceinline__ int rfl(int v) { return __builtin_amdgcn_readfirstlane(v); }
__device__ __forceinline__ u16 f2bf(float f) {
    u32 u = __float_as_uint(f);
    u32 r = (u + 0x7FFFu + ((u >> 16) & 1u)) >> 16;
    return (u16)r;
}
__device__ __forceinline__ float bf2f(u16 h) { return __uint_as_float((u32)h << 16); }

// ================= bucketed CSR build, 512 fixed-capacity buckets of 512 nodes ===========
// tmp item = src(18b) | k(3b)<<18 | dstlocal(9b)<<21 ; bucket = target >> 9
// final entry = (k<<28) | (src<<7)

__global__ void k_init_cur(u32* __restrict__ g) {
    int i = blockIdx.x * 256 + threadIdx.x;
    if (i < 512) g[i] = (u32)i << 14;     // b * BCAP
}

// single-pass: 8 edges/thread in registers; 2048 blocks for latency hiding
__global__ __launch_bounds__(256)
void k_passA(const int* __restrict__ ei, const int* __restrict__ ty, int E,
             u32* __restrict__ gcursor, u32* __restrict__ tmpItems) {
    __shared__ u32 hist[512], gb[512], cur[512];
    int tid = threadIdx.x;
    int e0 = blockIdx.x * 2048;
    int s[8], d[8], t[8];
#pragma unroll
    for (int i = 0; i < 8; i++) {
        int e = e0 + i * 256 + tid;
        if (e < E) { s[i] = ei[e]; d[i] = ei[E + e]; t[i] = ty[e]; }
        else t[i] = 0;
    }
    hist[tid] = 0; hist[tid + 256] = 0;
    __syncthreads();
#pragma unroll
    for (int i = 0; i < 8; i++) {
        if (t[i] >= 1) atomicAdd(&hist[(u32)d[i] >> 9], 1u);
        if (t[i] >= 2) atomicAdd(&hist[(u32)s[i] >> 9], 1u);
    }
    __syncthreads();
    u32 h0 = hist[tid], h1 = hist[tid + 256];
    gb[tid] = h0 ? atomicAdd(&gcursor[tid], h0) : 0u;
    gb[tid + 256] = h1 ? atomicAdd(&gcursor[tid + 256], h1) : 0u;
    cur[tid] = 0; cur[tid + 256] = 0;
    __syncthreads();
#pragma unroll
    for (int i = 0; i < 8; i++) {
        if (t[i] >= 1) {
            u32 b = (u32)d[i] >> 9;
            u32 slot = atomicAdd(&cur[b], 1u);
            u32 pos = gb[b] + slot;
            if (pos < ((b + 1u) << 14))
                tmpItems[pos] = (u32)s[i] | ((u32)(t[i] - 1) << 18) | (((u32)d[i] & 511u) << 21);
        }
        if (t[i] >= 2) {
            u32 b = (u32)s[i] >> 9;
            u32 slot = atomicAdd(&cur[b], 1u);
            u32 pos = gb[b] + slot;
            if (pos < ((b + 1u) << 14))
                tmpItems[pos] = (u32)d[i] | ((u32)(t[i] + 2) << 18) | (((u32)s[i] & 511u) << 21);
        }
    }
}

// ---- passB: per-(node,k) degree counts -> dinv (f32 + bf16) + kcnt[8N] ----
__global__ __launch_bounds__(256)
void k_passB(const u32* __restrict__ tmpItems, const u32* __restrict__ bucketEnd,
             float* __restrict__ dinv, u16* __restrict__ dinv16,
             u32* __restrict__ kcnt, int N) {
    __shared__ u32 c[512 * 8];
    int b = blockIdx.x, tid = threadIdx.x;
    for (int i = tid; i < 4096; i += 256) c[i] = 0;
    __syncthreads();
    u32 beg = (u32)b << 14;
    u32 end = bucketEnd[b];
    u32 cap = beg + BCAP;
    if (end > cap) end = cap;
    for (u32 i = beg + tid; i < end; i += 256) {
        u32 it = tmpItems[i];
        atomicAdd(&c[(it >> 21) * 8 + ((it >> 18) & 7)], 1u);
    }
    __syncthreads();
    int nodeBase = b << 9;
    for (int i = tid; i < 4096; i += 256) kcnt[(size_t)b * 4096 + i] = c[i];
    for (int l = tid; l < 512; l += 256) {
        int n = nodeBase + l;
#pragma unroll
        for (int k = 0; k < 7; k++) {
            float v = rsqrtf(1.0f + (float)c[l * 8 + k]);
            dinv[k * N + n] = v;
            dinv16[k * N + n] = f2bf(v);
        }
    }
}

// ---------------- scan over 8N elems, 8192/block, 256 blocks ----------------
__global__ __launch_bounds__(256)
void k_scan1(const u32* __restrict__ kcnt, u32* __restrict__ kofs, u32* __restrict__ bsums) {
    __shared__ u32 lds[256];
    int t = threadIdx.x;
    size_t base = (size_t)blockIdx.x * 8192 + (size_t)t * 32;
    u32 v[32];
    u32 s = 0;
    const uint4* src = (const uint4*)(kcnt + base);
#pragma unroll
    for (int q = 0; q < 8; q++) {
        uint4 c4 = src[q];
        v[q * 4 + 0] = s; s += c4.x;
        v[q * 4 + 1] = s; s += c4.y;
        v[q * 4 + 2] = s; s += c4.z;
        v[q * 4 + 3] = s; s += c4.w;
    }
    lds[t] = s; __syncthreads();
    for (int off = 1; off < 256; off <<= 1) {
        u32 x2 = (t >= off) ? lds[t - off] : 0u;
        __syncthreads();
        lds[t] += x2;
        __syncthreads();
    }
    u32 texcl = lds[t] - s;
    uint4* dst = (uint4*)(kofs + base);
#pragma unroll
    for (int q = 0; q < 8; q++) {
        uint4 o;
        o.x = v[q * 4 + 0] + texcl; o.y = v[q * 4 + 1] + texcl;
        o.z = v[q * 4 + 2] + texcl; o.w = v[q * 4 + 3] + texcl;
        dst[q] = o;
    }
    if (t == 255) bsums[blockIdx.x] = lds[255];
}

__global__ void k_scan2(const u32* __restrict__ bsums, u32* __restrict__ bexcl, int nb) {
    __shared__ u32 lds[256];
    int t = threadIdx.x;
    u32 v = (t < nb) ? bsums[t] : 0u;
    lds[t] = v; __syncthreads();
    for (int off = 1; off < 256; off <<= 1) {
        u32 x2 = (t >= off) ? lds[t - off] : 0u;
        __syncthreads();
        lds[t] += x2;
        __syncthreads();
    }
    if (t < nb) bexcl[t] = lds[t] - v;
}

__global__ __launch_bounds__(256)
void k_scan3(u32* __restrict__ kofs, const u32* __restrict__ bexcl,
             const u32* __restrict__ bsums, u32 M) {
    int t = threadIdx.x;
    size_t base = (size_t)blockIdx.x * 8192 + (size_t)t * 32;
    u32 add = bexcl[blockIdx.x];
    uint4* p4 = (uint4*)(kofs + base);
#pragma unroll
    for (int q = 0; q < 8; q++) {
        uint4 o = p4[q];
        o.x += add; o.y += add; o.z += add; o.w += add;
        p4[q] = o;
    }
    if (blockIdx.x == 255 && t == 255) kofs[M] = add + bsums[255];
}

// ---- passC-lite: scatter entries into final CSR positions (k-sorted, pre-scaled) ----
__global__ __launch_bounds__(256)
void k_passC(const u32* __restrict__ tmpItems, const u32* __restrict__ bucketEnd,
             const u32* __restrict__ kofs, u32* __restrict__ entries) {
    __shared__ u32 cur[4096];
    int b = blockIdx.x, tid = threadIdx.x;
    for (int i = tid; i < 4096; i += 256) cur[i] = kofs[(size_t)b * 4096 + i];
    __syncthreads();
    u32 beg = (u32)b << 14;
    u32 end = bucketEnd[b];
    u32 cap = beg + BCAP;
    if (end > cap) end = cap;
    for (u32 i = beg + tid; i < end; i += 256) {
        u32 it = tmpItems[i];
        u32 k = (it >> 18) & 7u;
        u32 src = it & 0x3FFFFu;
        u32 p = atomicAdd(&cur[(it >> 21) * 8 + k], 1u);
        entries[p] = (k << 28) | (src << 7);
    }
}

// ---- coef16 (coalesced) + depth-1 P/Q: one thread per (node,k) segment ----
__global__ __launch_bounds__(256)
void k_coef_pq(const u32* __restrict__ entries, const u32* __restrict__ kofs,
               const u16* __restrict__ dinv16, const float* __restrict__ dinv,
               const float* __restrict__ x, u16* __restrict__ coef16,
               float* __restrict__ P, float* __restrict__ Q, int N) {
    int i = blockIdx.x * 256 + threadIdx.x;          // (node,k) slot, k = i&7
    int k = i & 7, n = i >> 3;
    if (k == 7) return;                              // unused slot
    u32 beg = kofs[i], end = kofs[i + 1];
    float sP = 0.f, sQ = 0.f;
    for (u32 p = beg; p < end; ++p) {
        u32 src = (entries[p] >> 7) & 0x3FFFFu;
        u16 cb = dinv16[(size_t)k * N + src];        // L2-resident (3.7 MB)
        coef16[p] = cb;
        float cf = bf2f(cb);
        sP += cf * x[src];
        sQ += cf;
    }
    float dk = dinv[k * N + n];
    float xn = x[n];
    P[i] = dk * (sP + dk * xn);
    Q[i] = dk * (sQ + dk);
}

// ================= small prep kernels =================
__global__ void k_bsum(Ptr7 b, float* __restrict__ bsum) {
    int d = threadIdx.x;
    float s = 0.f;
#pragma unroll
    for (int k = 0; k < 7; k++) s += b.p[k][d];
    bsum[d] = s;
}

__global__ void k_uv(const float* __restrict__ nW, const float* __restrict__ nb,
                     Ptr7 W, float* __restrict__ U, float* __restrict__ V) {
    int k = blockIdx.x, d = threadIdx.x;
    const float* Wk = W.p[k];
    float u = 0.f, v = 0.f;
#pragma unroll 8
    for (int j = 0; j < 64; j++) {
        float w = Wk[j * 64 + d];
        u += nW[j] * w;
        v += nb[j] * w;
    }
    U[k * 64 + d] = u;
    V[k * 64 + d] = v;
}

// pack W into MFMA B-fragment order
__global__ void k_packW(Ptr7 W, u16* __restrict__ Wp) {
    int k = blockIdx.x;
    int tid = threadIdx.x;                 // 512 threads
    int ks = tid >> 8, ct = (tid >> 6) & 3, l = tid & 63;
    const float* Wk = W.p[k];
    u16* dst = Wp + (((size_t)(k * 2 + ks) * 4 + ct) * 512 + l * 8);
    int row0 = ks * 32 + (l >> 4) * 8;
    int col = ct * 16 + (l & 15);
#pragma unroll
    for (int i = 0; i < 8; i++) dst[i] = f2bf(Wk[(row0 + i) * 64 + col]);
}

// ---------------- h1 = relu(P@U + Q@V + bsum) -> bf16 ----------------
__global__ __launch_bounds__(256)
void k_h1(const float* __restrict__ P, const float* __restrict__ Q,
          const float* __restrict__ U, const float* __restrict__ V,
          const float* __restrict__ bsum, u16* __restrict__ h1) {
    int i = blockIdx.x * 256 + threadIdx.x;
    int n = rfl(i >> 6);
    int d = i & 63;
    float acc = bsum[d];
#pragma unroll
    for (int k = 0; k < 7; k++)
        acc += P[n * 8 + k] * U[k * 64 + d] + Q[n * 8 + k] * V[k * 64 + d];
    h1[((size_t)n << 6) + d] = f2bf(fmaxf(acc, 0.f));
}

// ======== fused gather + MFMA GEMM (depths 2,3): 512 thr / 32 nodes / 29 KB LDS ========
#define GACC(PK, CB, HV)                                             \
    {                                                                \
        float cf_ = __uint_as_float((u32)(CB) << 16);                \
        switch ((PK) >> 28) {                                        \
            case 0: a0 = fmaf(cf_, (HV), a0); break;                 \
            case 1: a1 = fmaf(cf_, (HV), a1); break;                 \
            case 2: a2 = fmaf(cf_, (HV), a2); break;                 \
            case 3: a3 = fmaf(cf_, (HV), a3); break;                 \
            case 4: a4 = fmaf(cf_, (HV), a4); break;                 \
            case 5: a5 = fmaf(cf_, (HV), a5); break;                 \
            default: a6 = fmaf(cf_, (HV), a6); break;                \
        }                                                            \
    }
// byte-offset addressing: (pk & 0x0FFFFFFF) is wave-uniform byte offset (src<<7);
// per-lane part is lane*2 -> saddr-form global_load_ushort
#define HLOAD(PK) bf2f(*(const u16*)(hcb + ((PK) & 0x0FFFFFFFu) + lb))
#define RL(V, J) ((u32)__builtin_amdgcn_readlane((int)(V), (J)))

__global__ __launch_bounds__(512, 8)
void k_fused(const u16* __restrict__ h, const u32* __restrict__ entries,
             const u16* __restrict__ coef16, const u32* __restrict__ kofs,
             const float* __restrict__ dinv, const u16* __restrict__ Wp,
             const float* __restrict__ bsum, u16* __restrict__ hout, int N) {
    __shared__ u16 mlds[32 * 456];      // [node][456] (448 + 8 pad)
    int tid = threadIdx.x;
    int w = tid >> 6, lane = tid & 63;
    int nb = blockIdx.x << 5;           // 32 nodes per block
    const char* hcb = (const char*)h;
    int lb = lane * 2;

    // ---- phase 1: each of 8 waves gathers 4 nodes ----
    for (int rr = 0; rr < 4; ++rr) {
        int nn = (w << 2) + rr;
        int n = nb + nn;
        u32 beg = (u32)rfl((int)kofs[(size_t)n << 3]);
        u32 end = (u32)rfl((int)kofs[((size_t)n << 3) + 7]);
        float hv = bf2f(h[((size_t)n << 6) + lane]);
        float d0 = dinv[n],         d1 = dinv[N + n],     d2 = dinv[2 * N + n];
        float d3 = dinv[3 * N + n], d4 = dinv[4 * N + n], d5 = dinv[5 * N + n];
        float d6 = dinv[6 * N + n];
        float a0 = d0 * hv, a1 = d1 * hv, a2 = d2 * hv, a3 = d3 * hv;
        float a4 = d4 * hv, a5 = d5 * hv, a6 = d6 * hv;

        u32 base = beg;
        u32 e = 0, cfw = 0;
        if (base + (u32)lane < end) {
            e = __builtin_nontemporal_load(&entries[base + lane]);
            cfw = (u32)__builtin_nontemporal_load(&coef16[base + lane]);
        }
        while (base < end) {
            u32 rem = end - base;
            int cnt = (rem < 64u) ? (int)rem : 64;
            u32 nb2 = base + 64;
            u32 en = 0, cfn = 0;
            if (nb2 + (u32)lane < end) {            // prefetch next batch
                en = __builtin_nontemporal_load(&entries[nb2 + lane]);
                cfn = (u32)__builtin_nontemporal_load(&coef16[nb2 + lane]);
            }
            int j = 0;
            for (; j + 16 <= cnt; j += 16) {        // 16-deep load ILP
                u32 pk0 = RL(e, j + 0),  pk1 = RL(e, j + 1),  pk2 = RL(e, j + 2),  pk3 = RL(e, j + 3);
                u32 pk4 = RL(e, j + 4),  pk5 = RL(e, j + 5),  pk6 = RL(e, j + 6),  pk7 = RL(e, j + 7);
                u32 pk8 = RL(e, j + 8),  pk9 = RL(e, j + 9),  pkA = RL(e, j + 10), pkB = RL(e, j + 11);
                u32 pkC = RL(e, j + 12), pkD = RL(e, j + 13), pkE = RL(e, j + 14), pkF = RL(e, j + 15);
                u32 cb0 = RL(cfw, j + 0),  cb1 = RL(cfw, j + 1),  cb2 = RL(cfw, j + 2),  cb3 = RL(cfw, j + 3);
                u32 cb4 = RL(cfw, j + 4),  cb5 = RL(cfw, j + 5),  cb6 = RL(cfw, j + 6),  cb7 = RL(cfw, j + 7);
                u32 cb8 = RL(cfw, j + 8),  cb9 = RL(cfw, j + 9),  cbA = RL(cfw, j + 10), cbB = RL(cfw, j + 11);
                u32 cbC = RL(cfw, j + 12), cbD = RL(cfw, j + 13), cbE = RL(cfw, j + 14), cbF = RL(cfw, j + 15);
                float h0 = HLOAD(pk0), h1v = HLOAD(pk1), h2v = HLOAD(pk2), h3v = HLOAD(pk3);
                float h4v = HLOAD(pk4), h5v = HLOAD(pk5), h6v = HLOAD(pk6), h7v = HLOAD(pk7);
                float h8v = HLOAD(pk8), h9v = HLOAD(pk9), hAv = HLOAD(pkA), hBv = HLOAD(pkB);
                float hCv = HLOAD(pkC), hDv = HLOAD(pkD), hEv = HLOAD(pkE), hFv = HLOAD(pkF);
                GACC(pk0, cb0, h0)  GACC(pk1, cb1, h1v) GACC(pk2, cb2, h2v) GACC(pk3, cb3, h3v)
                GACC(pk4, cb4, h4v) GACC(pk5, cb5, h5v) GACC(pk6, cb6, h6v) GACC(pk7, cb7, h7v)
                GACC(pk8, cb8, h8v) GACC(pk9, cb9, h9v) GACC(pkA, cbA, hAv) GACC(pkB, cbB, hBv)
                GACC(pkC, cbC, hCv) GACC(pkD, cbD, hDv) GACC(pkE, cbE, hEv) GACC(pkF, cbF, hFv)
            }
            for (; j + 8 <= cnt; j += 8) {
                u32 pk0 = RL(e, j + 0), pk1 = RL(e, j + 1), pk2 = RL(e, j + 2), pk3 = RL(e, j + 3);
                u32 pk4 = RL(e, j + 4), pk5 = RL(e, j + 5), pk6 = RL(e, j + 6), pk7 = RL(e, j + 7);
                u32 cb0 = RL(cfw, j + 0), cb1 = RL(cfw, j + 1), cb2 = RL(cfw, j + 2), cb3 = RL(cfw, j + 3);
                u32 cb4 = RL(cfw, j + 4), cb5 = RL(cfw, j + 5), cb6 = RL(cfw, j + 6), cb7 = RL(cfw, j + 7);
                float h0 = HLOAD(pk0), h1v = HLOAD(pk1), h2v = HLOAD(pk2), h3v = HLOAD(pk3);
                float h4v = HLOAD(pk4), h5v = HLOAD(pk5), h6v = HLOAD(pk6), h7v = HLOAD(pk7);
                GACC(pk0, cb0, h0)  GACC(pk1, cb1, h1v) GACC(pk2, cb2, h2v) GACC(pk3, cb3, h3v)
                GACC(pk4, cb4, h4v) GACC(pk5, cb5, h5v) GACC(pk6, cb6, h6v) GACC(pk7, cb7, h7v)
            }
            for (; j < cnt; ++j) {
                u32 pk = RL(e, j);
                u32 cb = RL(cfw, j);
                float hval = HLOAD(pk);
                GACC(pk, cb, hval)
            }
            e = en; cfw = cfn; base = nb2;
        }

        u16* mp = mlds + nn * 456 + lane;
        mp[0]   = f2bf(d0 * a0); mp[64]  = f2bf(d1 * a1); mp[128] = f2bf(d2 * a2);
        mp[192] = f2bf(d3 * a3); mp[256] = f2bf(d4 * a4); mp[320] = f2bf(d5 * a5);
        mp[384] = f2bf(d6 * a6);
    }
    __syncthreads();

    // ---- phase 2: [32,448] x [448,64] MFMA GEMM + bias + relu ----
    int rg = w >> 2, cq = w & 3;        // 8 waves: 2 row-groups x 4 col-quads
    const u16* bp = Wp + (size_t)cq * 512 + (size_t)lane * 8;
    const u16* arow = mlds + (rg * 16 + (lane & 15)) * 456 + ((lane >> 4) << 3);
    f32x4 acc = {0, 0, 0, 0};
#pragma unroll
    for (int kk = 0; kk < 14; kk++) {
        bf16x8 a = *(const bf16x8*)(arow + kk * 32);
        bf16x8 b = *(const bf16x8*)(bp + (size_t)kk * 4 * 512);
        acc = __builtin_amdgcn_mfma_f32_16x16x32_bf16(a, b, acc, 0, 0, 0);
    }
    int col = cq * 16 + (lane & 15);
    int row0 = nb + rg * 16 + ((lane >> 4) << 2);
    float bv = bsum[col];
#pragma unroll
    for (int reg = 0; reg < 4; reg++) {
        float vv = fmaxf(acc[reg] + bv, 0.f);
        hout[(size_t)(row0 + reg) * 64 + col] = f2bf(vv);
    }
}

// ---------------- pooling + 2-layer MLP head (bf16 h) ----------------
__global__ __launch_bounds__(256)
void k_head(const u16* __restrict__ h, const float* __restrict__ w1,
            const float* __restrict__ b1, const float* __restrict__ w2,
            const float* __restrict__ b2, float* __restrict__ out) {
    __shared__ float gmax[4][64];
    __shared__ float gl[64];
    __shared__ float t1p[4][64];
    int b = blockIdx.x;
    int tid = threadIdx.x;
    int d = tid & 63, rg = tid >> 6;
    const u16* hb = h + (size_t)b * 64 * 64;
    float pm = -1e30f;
#pragma unroll
    for (int i = 0; i < 16; i++) pm = fmaxf(pm, bf2f(hb[(rg * 16 + i) * 64 + d]));
    gmax[rg][d] = pm; __syncthreads();
    if (rg == 0) gl[d] = fmaxf(fmaxf(gmax[0][d], gmax[1][d]), fmaxf(gmax[2][d], gmax[3][d]));
    __syncthreads();
    float s = 0.f;
#pragma unroll
    for (int i = 0; i < 16; i++) { int dd = rg * 16 + i; s += gl[dd] * w1[dd * 64 + d]; }
    t1p[rg][d] = s; __syncthreads();
    if (rg == 0) {
        float t1 = fmaxf(t1p[0][d] + t1p[1][d] + t1p[2][d] + t1p[3][d] + b1[d], 0.f);
        float v = t1 * w2[d];
        for (int off = 32; off; off >>= 1) v += __shfl_down(v, off, 64);
        if (d == 0) out[b] = v + b2[0];
    }
}

extern "C" void kernel_launch(void* const* d_in, const int* in_sizes, int n_in,
                              void* d_out, int out_size, void* d_ws, size_t ws_size,
                              hipStream_t stream) {
    const float* x     = (const float*)d_in[0];
    const int*   ei    = (const int*)d_in[1];
    const int*   ty    = (const int*)d_in[2];
    const float* nodeW = (const float*)d_in[3];
    const float* nodeb = (const float*)d_in[4];
    const float* out1W = (const float*)d_in[5];
    const float* out1b = (const float*)d_in[6];
    const float* out2W = (const float*)d_in[7];
    const float* out2b = (const float*)d_in[8];

    Ptr7 W, B;
    W.p[0] = (const float*)d_in[9];  B.p[0] = (const float*)d_in[10];   // W1
    W.p[1] = (const float*)d_in[11]; B.p[1] = (const float*)d_in[12];   // W2
    W.p[2] = (const float*)d_in[13]; B.p[2] = (const float*)d_in[14];   // W3
    W.p[3] = (const float*)d_in[15]; B.p[3] = (const float*)d_in[16];   // W4
    W.p[4] = (const float*)d_in[17]; B.p[4] = (const float*)d_in[18];   // W2b
    W.p[5] = (const float*)d_in[19]; B.p[5] = (const float*)d_in[20];   // W3b
    W.p[6] = (const float*)d_in[21]; B.p[6] = (const float*)d_in[22];   // W4b

    const int N = in_sizes[0];       // 262144
    const int E = in_sizes[2];       // 4194304

    char* p = (char*)d_ws;
    auto carve = [&](size_t bytes) { void* r = (void*)p; p += (bytes + 255) & ~(size_t)255; return r; };
    u16*   hA       = (u16*)carve((size_t)N * 64 * 2);
    u16*   hB       = (u16*)carve((size_t)N * 64 * 2);
    u32*   entries  = (u32*)carve((size_t)2 * E * 4 + 256);
    u16*   coef16   = (u16*)carve((size_t)2 * E * 2 + 128);
    float* dinv     = (float*)carve((size_t)7 * N * 4);
    u16*   dinv16   = (u16*)carve((size_t)7 * N * 2);
    u32*   kcnt     = (u32*)carve((size_t)8 * N * 4);
    u32*   kofs     = (u32*)carve(((size_t)8 * N + 1) * 4);
    float* P        = (float*)carve((size_t)N * 8 * 4);
    float* Q        = (float*)carve((size_t)N * 8 * 4);
    float* U        = (float*)carve(7 * 64 * 4);
    float* V        = (float*)carve(7 * 64 * 4);
    float* bsum     = (float*)carve(256);
    u16*   Wp       = (u16*)carve((size_t)7 * 2 * 4 * 512 * 2);
    u32*   gcursor  = (u32*)carve(512 * 4);
    u32*   bsums    = (u32*)carve(1024);
    u32*   bexcl    = (u32*)carve(1024);
    // tmpItems (512*BCAP u32 = 33.5 MB, dead after passC) lives in the free tail
    u32*   tmpItems = (u32*)p;
    (void)n_in; (void)out_size; (void)ws_size;

    // ---- bucketed CSR build ----
    k_init_cur<<<2, 256, 0, stream>>>(gcursor);
    k_passA<<<(E + 2047) / 2048, 256, 0, stream>>>(ei, ty, E, gcursor, tmpItems);
    k_passB<<<512, 256, 0, stream>>>(tmpItems, gcursor, dinv, dinv16, kcnt, N);
    k_scan1<<<256, 256, 0, stream>>>(kcnt, kofs, bsums);
    k_scan2<<<1, 256, 0, stream>>>(bsums, bexcl, 256);
    k_scan3<<<256, 256, 0, stream>>>(kofs, bexcl, bsums, (u32)8 * N);
    k_passC<<<512, 256, 0, stream>>>(tmpItems, gcursor, kofs, entries);
    k_coef_pq<<<(8 * N) / 256, 256, 0, stream>>>(entries, kofs, dinv16, dinv, x,
                                                 coef16, P, Q, N);

    k_bsum<<<1, 64, 0, stream>>>(B, bsum);
    k_uv<<<7, 64, 0, stream>>>(nodeW, nodeb, W, U, V);
    k_packW<<<7, 512, 0, stream>>>(W, Wp);

    // depth 1 via rank-2 shortcut (P/Q computed in k_coef_pq)
    k_h1<<<(N * 64) / 256, 256, 0, stream>>>(P, Q, U, V, bsum, hA);

    // depths 2,3: fused gather + MFMA GEMM (full occupancy: 512 thr, 29 KB LDS)
    k_fused<<<N / 32, 512, 0, stream>>>(hA, entries, coef16, kofs, dinv, Wp, bsum, hB, N);
    k_fused<<<N / 32, 512, 0, stream>>>(hB, entries, coef16, kofs, dinv, Wp, bsum, hA, N);

    k_head<<<N / 64, 256, 0, stream>>>(hA, out1W, out1b, out2W, out2b, (float*)d_out);
}